// Round 1
// baseline (137.072 us; speedup 1.0000x reference)
//
#include <hip/hip_runtime.h>
#include <math.h>

#define BINS 30
#define QDIM 32
#define DDIM 8192

__global__ __launch_bounds__(256) void drmm_hist_kernel(
    const float* __restrict__ simmat,
    const int*   __restrict__ dtoks,
    const int*   __restrict__ qtoks,
    float*       __restrict__ out)
{
    const int bq = blockIdx.x;        // row index in [0, B*Q)
    const int b  = bq >> 5;           // Q == 32
    const int t  = threadIdx.x;

    __shared__ int hist[BINS];
    if (t < BINS) hist[t] = 0;
    __syncthreads();

    const int  qtok   = qtoks[bq];    // qtoks[b*Q + q] flattened == qtoks[bq]
    const bool qvalid = (qtok != 0);

    const float4* __restrict__ srow = reinterpret_cast<const float4*>(simmat + (size_t)bq * DDIM);
    const int4*   __restrict__ drow = reinterpret_cast<const int4*>(dtoks + (size_t)b * DDIM);

    int cnt[BINS];
#pragma unroll
    for (int i = 0; i < BINS; ++i) cnt[i] = 0;

    // 8192 elements / (256 threads * 4 per thread) = 8 iterations
#pragma unroll
    for (int it = 0; it < 8; ++it) {
        const int v = it * 256 + t;   // float4 index within row
        const float4 s  = srow[v];
        const int4   dt = drow[v];

        // bin = trunc(((s + 1.000001f) / 2.0f) * 29.0f), matching XLA f32 op order.
        // Invalid (padded) elements get bin = BINS so they never match a ballot.
        int bin0 = (int)(((s.x + 1.000001f) / 2.0f) * 29.0f);
        int bin1 = (int)(((s.y + 1.000001f) / 2.0f) * 29.0f);
        int bin2 = (int)(((s.z + 1.000001f) / 2.0f) * 29.0f);
        int bin3 = (int)(((s.w + 1.000001f) / 2.0f) * 29.0f);
        bin0 = (qvalid && dt.x != 0) ? bin0 : BINS;
        bin1 = (qvalid && dt.y != 0) ? bin1 : BINS;
        bin2 = (qvalid && dt.z != 0) ? bin2 : BINS;
        bin3 = (qvalid && dt.w != 0) ? bin3 : BINS;

#pragma unroll
        for (int i = 0; i < BINS; ++i) {
            cnt[i] += __popcll(__ballot(bin0 == i));
            cnt[i] += __popcll(__ballot(bin1 == i));
            cnt[i] += __popcll(__ballot(bin2 == i));
            cnt[i] += __popcll(__ballot(bin3 == i));
        }
    }

    // cnt[] is wave-uniform (ballot results). Lane 0 of each of the 4 waves
    // merges into the block histogram.
    if ((t & 63) == 0) {
#pragma unroll
        for (int i = 0; i < BINS; ++i) atomicAdd(&hist[i], cnt[i]);
    }
    __syncthreads();

    if (t < BINS) {
        out[(size_t)bq * BINS + t] = logf((float)hist[t] + 1e-5f);
    }
}

extern "C" void kernel_launch(void* const* d_in, const int* in_sizes, int n_in,
                              void* d_out, int out_size, void* d_ws, size_t ws_size,
                              hipStream_t stream) {
    const float* simmat = (const float*)d_in[0];  // [B,Q,D] f32
    const int*   dtoks  = (const int*)d_in[1];    // [B,D]
    const int*   qtoks  = (const int*)d_in[2];    // [B,Q]
    float*       out    = (float*)d_out;          // [B,Q,BINS]

    const int BQ = in_sizes[2];                   // B*Q = 4096
    drmm_hist_kernel<<<BQ, 256, 0, stream>>>(simmat, dtoks, qtoks, out);
}

// Round 2
// 32.685 us; speedup vs baseline: 4.1937x; 4.1937x over previous
//
#include <hip/hip_runtime.h>
#include <math.h>

#define BINS 30
#define QDIM 32
#define DDIM 8192

// One block per (b,q) row. 256 threads = 4 waves.
// Per-wave privatized LDS histogram (padded to 32 words) updated with
// DS atomics; merged + log'd by threads 0..29 at the end.
__global__ __launch_bounds__(256) void drmm_hist_kernel(
    const float* __restrict__ simmat,
    const int*   __restrict__ dtoks,
    const int*   __restrict__ qtoks,
    float*       __restrict__ out)
{
    const int bq = blockIdx.x;        // row index in [0, B*Q)
    const int b  = bq >> 5;           // Q == 32
    const int t  = threadIdx.x;
    const int wv = t >> 6;            // wave id 0..3

    __shared__ int hist[4][32];       // 4 waves x 30 bins (padded)
    // init: 128 words, threads 0..127 clear one each
    if (t < 128) ((int*)hist)[t] = 0;
    __syncthreads();

    const bool qvalid = (qtoks[bq] != 0);

    const float4* __restrict__ srow = reinterpret_cast<const float4*>(simmat + (size_t)bq * DDIM);
    const int4*   __restrict__ drow = reinterpret_cast<const int4*>(dtoks + (size_t)b * DDIM);

    int* __restrict__ h = hist[wv];

    // 8192 elements / (256 threads * 4 per thread) = 8 iterations
#pragma unroll
    for (int it = 0; it < 8; ++it) {
        const int v = it * 256 + t;   // float4 index within row
        const float4 s  = srow[v];
        const int4   dt = drow[v];

        // bin = trunc(((s + 1.000001f) / 2.0f) * 29.0f)  -- matches XLA f32 op order
        int bin0 = (int)(((s.x + 1.000001f) / 2.0f) * 29.0f);
        int bin1 = (int)(((s.y + 1.000001f) / 2.0f) * 29.0f);
        int bin2 = (int)(((s.z + 1.000001f) / 2.0f) * 29.0f);
        int bin3 = (int)(((s.w + 1.000001f) / 2.0f) * 29.0f);
        // clamp for LDS safety (no-op for inputs in [-1,1])
        bin0 = min(max(bin0, 0), BINS - 1);
        bin1 = min(max(bin1, 0), BINS - 1);
        bin2 = min(max(bin2, 0), BINS - 1);
        bin3 = min(max(bin3, 0), BINS - 1);

        if (qvalid) {
            if (dt.x != 0) atomicAdd(&h[bin0], 1);
            if (dt.y != 0) atomicAdd(&h[bin1], 1);
            if (dt.z != 0) atomicAdd(&h[bin2], 1);
            if (dt.w != 0) atomicAdd(&h[bin3], 1);
        }
    }
    __syncthreads();

    if (t < BINS) {
        const int c = hist[0][t] + hist[1][t] + hist[2][t] + hist[3][t];
        out[(size_t)bq * BINS + t] = logf((float)c + 1e-5f);
    }
}

extern "C" void kernel_launch(void* const* d_in, const int* in_sizes, int n_in,
                              void* d_out, int out_size, void* d_ws, size_t ws_size,
                              hipStream_t stream) {
    const float* simmat = (const float*)d_in[0];  // [B,Q,D] f32
    const int*   dtoks  = (const int*)d_in[1];    // [B,D]
    const int*   qtoks  = (const int*)d_in[2];    // [B,Q]
    float*       out    = (float*)d_out;          // [B,Q,BINS]

    const int BQ = in_sizes[2];                   // B*Q = 4096
    drmm_hist_kernel<<<BQ, 256, 0, stream>>>(simmat, dtoks, qtoks, out);
}

// Round 3
// 32.556 us; speedup vs baseline: 4.2103x; 1.0040x over previous
//
#include <hip/hip_runtime.h>
#include <math.h>

#define BINS 30
#define QDIM 32
#define DDIM 8192
#define MASK_WORDS_PER_ROW 256   // 8192 bits / 32

// ---------- kernel 1: dtoks -> validity bitmask (one bit per token) ----------
// mask u32 word w of row b: bit j = (dtoks[b][32w + j] != 0)
__global__ __launch_bounds__(256) void build_mask_kernel(
    const int* __restrict__ dtoks,
    unsigned int* __restrict__ mask)
{
    const int gid = blockIdx.x * 256 + threadIdx.x;   // one thread per token
    const int tok = dtoks[gid];
    const unsigned long long bal = __ballot(tok != 0);
    if ((threadIdx.x & 63) == 0) {
        // wave covers tokens [gid, gid+64); little-endian u64 = words 2k, 2k+1
        reinterpret_cast<unsigned long long*>(mask)[gid >> 6] = bal;
    }
}

// ---------- kernel 2: weighted histogram + log ----------
// One block per (b,q) row. 256 threads = 4 waves.
// Hot loop: 1 float4 global load + 1 broadcast LDS mask read + LDS atomics.
__global__ __launch_bounds__(256) void drmm_hist_kernel(
    const float* __restrict__ simmat,
    const unsigned int* __restrict__ mask,
    const int*   __restrict__ qtoks,
    float*       __restrict__ out)
{
    const int bq = blockIdx.x;        // row index in [0, B*Q)
    const int b  = bq >> 5;           // Q == 32
    const int t  = threadIdx.x;
    const int wv = t >> 6;            // wave id 0..3

    __shared__ int hist[4][32];               // 4 waves x 30 bins (padded)
    __shared__ unsigned int mask_lds[MASK_WORDS_PER_ROW];

    if (t < 128) ((int*)hist)[t] = 0;
    mask_lds[t] = mask[b * MASK_WORDS_PER_ROW + t];   // 1 KB row mask
    __syncthreads();

    const bool qvalid = (qtoks[bq] != 0);

    if (qvalid) {
        const float4* __restrict__ srow =
            reinterpret_cast<const float4*>(simmat + (size_t)bq * DDIM);
        int* __restrict__ h = hist[wv];

        // 8192 elements / (256 threads * 4 per thread) = 8 iterations
#pragma unroll
        for (int it = 0; it < 8; ++it) {
            const int v = it * 256 + t;       // float4 index within row
            const float4 s = srow[v];
            // word v>>3 covers float4s [8k, 8k+8); nibble (v&7) is ours.
            const unsigned int bits =
                (mask_lds[it * 32 + (t >> 3)] >> ((t & 7) * 4)) & 0xFu;

            // bin = trunc(((s + 1.000001f) / 2.0f) * 29.0f) -- XLA f32 op order
            int bin0 = (int)(((s.x + 1.000001f) / 2.0f) * 29.0f);
            int bin1 = (int)(((s.y + 1.000001f) / 2.0f) * 29.0f);
            int bin2 = (int)(((s.z + 1.000001f) / 2.0f) * 29.0f);
            int bin3 = (int)(((s.w + 1.000001f) / 2.0f) * 29.0f);
            // clamp for LDS safety (no-op for inputs in [-1,1])
            bin0 = min(max(bin0, 0), BINS - 1);
            bin1 = min(max(bin1, 0), BINS - 1);
            bin2 = min(max(bin2, 0), BINS - 1);
            bin3 = min(max(bin3, 0), BINS - 1);

            if (bits & 1u) atomicAdd(&h[bin0], 1);
            if (bits & 2u) atomicAdd(&h[bin1], 1);
            if (bits & 4u) atomicAdd(&h[bin2], 1);
            if (bits & 8u) atomicAdd(&h[bin3], 1);
        }
    }
    __syncthreads();

    if (t < BINS) {
        const int c = hist[0][t] + hist[1][t] + hist[2][t] + hist[3][t];
        out[(size_t)bq * BINS + t] = logf((float)c + 1e-5f);
    }
}

extern "C" void kernel_launch(void* const* d_in, const int* in_sizes, int n_in,
                              void* d_out, int out_size, void* d_ws, size_t ws_size,
                              hipStream_t stream) {
    const float* simmat = (const float*)d_in[0];  // [B,Q,D] f32
    const int*   dtoks  = (const int*)d_in[1];    // [B,D]
    const int*   qtoks  = (const int*)d_in[2];    // [B,Q]
    float*       out    = (float*)d_out;          // [B,Q,BINS]

    const int BQ = in_sizes[2];                   // B*Q = 4096
    const int B  = BQ / QDIM;                     // 128
    const int ntok = B * DDIM;                    // 1,048,576 tokens

    unsigned int* mask = (unsigned int*)d_ws;     // B * 256 u32 = 128 KB

    build_mask_kernel<<<ntok / 256, 256, 0, stream>>>(dtoks, mask);
    drmm_hist_kernel<<<BQ, 256, 0, stream>>>(simmat, mask, qtoks, out);
}

// Round 4
// 31.367 us; speedup vs baseline: 4.3700x; 1.0379x over previous
//
#include <hip/hip_runtime.h>
#include <math.h>

#define BINS 30
#define QDIM 32
#define DDIM 8192
#define MASK_WORDS_PER_ROW 256   // 8192 bits / 32
#define NCOPY 8                  // histogram copies (collision dilution)

// ---------- kernel 1: dtoks -> validity bitmask (one bit per token) ----------
__global__ __launch_bounds__(256) void build_mask_kernel(
    const int* __restrict__ dtoks,
    unsigned int* __restrict__ mask)
{
    const int gid = blockIdx.x * 256 + threadIdx.x;   // one thread per token
    const int tok = dtoks[gid];
    const unsigned long long bal = __ballot(tok != 0);
    if ((threadIdx.x & 63) == 0) {
        reinterpret_cast<unsigned long long*>(mask)[gid >> 6] = bal;
    }
}

// ---------- kernel 2: weighted histogram + log ----------
// One block per (b,q) row. 256 threads = 4 waves.
// 8 shared histogram copies, interleaved bin-major: word = bin*8 + (t&7).
// Per wave-atomic only 8 lanes target each copy -> same-address multiplicity
// ~1-2 (was ~6), bank multiplicity ~2 (free per m136).
__global__ __launch_bounds__(256) void drmm_hist_kernel(
    const float* __restrict__ simmat,
    const unsigned int* __restrict__ mask,
    const int*   __restrict__ qtoks,
    float*       __restrict__ out)
{
    const int bq = blockIdx.x;        // row index in [0, B*Q)
    const int b  = bq >> 5;           // Q == 32
    const int t  = threadIdx.x;
    const int c  = t & (NCOPY - 1);   // this lane's histogram copy

    __shared__ int hist[BINS * NCOPY];            // 240 words, interleaved
    __shared__ unsigned int mask_lds[MASK_WORDS_PER_ROW];

    if (t < BINS * NCOPY) hist[t] = 0;
    mask_lds[t] = mask[b * MASK_WORDS_PER_ROW + t];   // 1 KB row mask
    __syncthreads();

    const bool qvalid = (qtoks[bq] != 0);

    if (qvalid) {
        const float4* __restrict__ srow =
            reinterpret_cast<const float4*>(simmat + (size_t)bq * DDIM);

        // 8192 elements / (256 threads * 4 per thread) = 8 iterations
#pragma unroll
        for (int it = 0; it < 8; ++it) {
            const int v = it * 256 + t;       // float4 index within row
            const float4 s = srow[v];
            const unsigned int bits =
                (mask_lds[it * 32 + (t >> 3)] >> ((t & 7) * 4)) & 0xFu;

            // bin = trunc(((s + 1.000001f) / 2.0f) * 29.0f) -- XLA f32 op order
            int bin0 = (int)(((s.x + 1.000001f) / 2.0f) * 29.0f);
            int bin1 = (int)(((s.y + 1.000001f) / 2.0f) * 29.0f);
            int bin2 = (int)(((s.z + 1.000001f) / 2.0f) * 29.0f);
            int bin3 = (int)(((s.w + 1.000001f) / 2.0f) * 29.0f);
            // clamp for LDS safety (no-op for inputs in [-1,1])
            bin0 = min(max(bin0, 0), BINS - 1);
            bin1 = min(max(bin1, 0), BINS - 1);
            bin2 = min(max(bin2, 0), BINS - 1);
            bin3 = min(max(bin3, 0), BINS - 1);

            if (bits & 1u) atomicAdd(&hist[bin0 * NCOPY + c], 1);
            if (bits & 2u) atomicAdd(&hist[bin1 * NCOPY + c], 1);
            if (bits & 4u) atomicAdd(&hist[bin2 * NCOPY + c], 1);
            if (bits & 8u) atomicAdd(&hist[bin3 * NCOPY + c], 1);
        }
    }
    __syncthreads();

    if (t < BINS) {
        const int* h = &hist[t * NCOPY];
        const int cnt = h[0] + h[1] + h[2] + h[3] + h[4] + h[5] + h[6] + h[7];
        out[(size_t)bq * BINS + t] = logf((float)cnt + 1e-5f);
    }
}

extern "C" void kernel_launch(void* const* d_in, const int* in_sizes, int n_in,
                              void* d_out, int out_size, void* d_ws, size_t ws_size,
                              hipStream_t stream) {
    const float* simmat = (const float*)d_in[0];  // [B,Q,D] f32
    const int*   dtoks  = (const int*)d_in[1];    // [B,D]
    const int*   qtoks  = (const int*)d_in[2];    // [B,Q]
    float*       out    = (float*)d_out;          // [B,Q,BINS]

    const int BQ = in_sizes[2];                   // B*Q = 4096
    const int B  = BQ / QDIM;                     // 128
    const int ntok = B * DDIM;                    // 1,048,576 tokens

    unsigned int* mask = (unsigned int*)d_ws;     // B * 256 u32 = 128 KB

    build_mask_kernel<<<ntok / 256, 256, 0, stream>>>(dtoks, mask);
    drmm_hist_kernel<<<BQ, 256, 0, stream>>>(simmat, mask, qtoks, out);
}